// Round 2
// baseline (853.084 us; speedup 1.0000x reference)
//
#include <hip/hip_runtime.h>

// Problem constants
#define BB 64
#define II 1152
#define OO 32
#define DD 8
#define HH 16
#define BOH (BB * OO * HH)    // 32768
#define WTILE (OO * DD * HH)  // 4096 floats per i

// Decomposition (R5-proven): NIC * IC == II
#define IC   9
#define NIC  128
#define NBB  16    // b per block
#define NBG  4     // b-groups (NBG * NBB == BB)
#define NJB  4     // b per thread

// ---------------------------------------------------------------------------
// DPP add helper (ctrl must be an ICE -> template param).
// ---------------------------------------------------------------------------
template<int CTRL>
__device__ __forceinline__ float dpp_add(float x)
{
    return x + __int_as_float(__builtin_amdgcn_update_dpp(
            0, __float_as_int(x), CTRL, 0xF, 0xF, false));
}

// Sum over each 16-lane row, result in every lane of the row (VALU only).
__device__ __forceinline__ float row_sum16(float x)
{
    x = dpp_add<0x121>(x);   // row_ror:1
    x = dpp_add<0x122>(x);   // row_ror:2
    x = dpp_add<0x124>(x);   // row_ror:4
    x = dpp_add<0x128>(x);   // row_ror:8
    return x;
}

// lane l gets x[l] + x[l^32] — v_permlane32_swap keeps this on the VALU pipe.
__device__ __forceinline__ float add_xor32(float x)
{
#if __has_builtin(__builtin_amdgcn_permlane32_swap)
    auto r = __builtin_amdgcn_permlane32_swap(
        __float_as_uint(x), __float_as_uint(x), false, false);
    return __uint_as_float(r[0]) + __uint_as_float(r[1]);
#else
    return x + __shfl_xor(x, 32, 64);
#endif
}

// lane l gets x[l] + x[l^16] — VALU permlane16_swap vs DS-pipe ds_swizzle.
__device__ __forceinline__ float add_xor16(float x)
{
#if __has_builtin(__builtin_amdgcn_permlane16_swap)
    auto r = __builtin_amdgcn_permlane16_swap(
        __float_as_uint(x), __float_as_uint(x), false, false);
    return __uint_as_float(r[0]) + __uint_as_float(r[1]);
#else
    return x + __int_as_float(__builtin_amdgcn_ds_swizzle(__float_as_int(x), 0x401F));
#endif
}

// ---------------------------------------------------------------------------
// XOR swizzle on a float index within one 4096-float W tile.
// f = o*128 + d*16 + h. XORs bits [4:2] with o&7 -> per-o ds_read_b128 starts
// spread uniformly over banks, while 16-B groups stay contiguous so
// global_load_lds can DMA a LINEAR LDS destination from a pre-swizzled
// global source (both-sides-same-involution rule).
// ---------------------------------------------------------------------------
__device__ __forceinline__ int wswz(int f) { return f ^ (((f >> 7) & 7) << 2); }

// Stage one 16 KB W tile global->LDS via DMA (no VGPR round trip, no ds_write).
__device__ __forceinline__ void stage_w_tile(const float* __restrict__ wg,
                                             float* __restrict__ wn, int tid)
{
    #pragma unroll
    for (int j = 0; j < 4; j++) {
        const int P = (tid + j * 256) * 4;    // linear LDS float index
        const int g = wswz(P);                // pre-swizzled global source
        __builtin_amdgcn_global_load_lds(
            (const __attribute__((address_space(1))) void*)(wg + g),
            (__attribute__((address_space(3))) void*)(wn + P),
            16, 0, 0);
    }
}

// ---------------------------------------------------------------------------
// Pass kernel: one routing iteration. Grid (NIC, NBG) = 512 blocks x 256 thr.
// tid = o + 32*hh + 64*bq. Logits are linear in v, so vsum (= v0 [+ v1])
// replaces any logits array; PASS 0 has uniform coupling 1/32.
// R2: IC loop fully unrolled; u double-buffered (u[i+1] loads issue during
// compute on u[i]) so the cold u-line latency leaves the post-barrier
// critical path. W staged by global_load_lds DMA (linear LDS, swizzled src).
// Softmax is pure-VALU (DPP + permlane swaps).
// ---------------------------------------------------------------------------
template<int PASS, bool ATOMIC>
__global__ __launch_bounds__(256, 2)
void pass_kernel(const float* __restrict__ u, const float* __restrict__ w,
                 const float* __restrict__ pv0, const float* __restrict__ pv1,
                 float* __restrict__ out)
{
    __shared__ __align__(16) float Wsh[2][WTILE];   // 2 x 16 KB, linear

    const int tid   = threadIdx.x;
    const int o     = tid & 31;
    const int hh    = (tid >> 5) & 1;
    const int bq    = tid >> 6;           // 0..3
    const int bbase = blockIdx.y * NBB;
    const int i0    = blockIdx.x * IC;
    const int hofs  = hh * 8;
    const int swm   = (o & 7) << 2;       // read-side XOR mask (floats)
    const int orow  = o * (DD * HH);

    // Kick off DMA for W[i0] immediately (overlaps vsum + u0 loads below).
    stage_w_tile(w + (size_t)i0 * WTILE, Wsh[0], tid);

    // vsum = sum of previous v's (constant over i).
    float vsum[NJB][8];
    if (PASS >= 1) {
        #pragma unroll
        for (int jb = 0; jb < NJB; jb++) {
            const int b = bbase + bq * NJB + jb;
            const float* p = pv0 + ((b * OO + o) * HH + hofs);
            float4 a = *(const float4*)p;
            float4 c = *(const float4*)(p + 4);
            vsum[jb][0] = a.x; vsum[jb][1] = a.y; vsum[jb][2] = a.z; vsum[jb][3] = a.w;
            vsum[jb][4] = c.x; vsum[jb][5] = c.y; vsum[jb][6] = c.z; vsum[jb][7] = c.w;
            if (PASS == 2) {
                const float* q = pv1 + ((b * OO + o) * HH + hofs);
                float4 a2 = *(const float4*)q;
                float4 c2 = *(const float4*)(q + 4);
                vsum[jb][0] += a2.x; vsum[jb][1] += a2.y; vsum[jb][2] += a2.z; vsum[jb][3] += a2.w;
                vsum[jb][4] += c2.x; vsum[jb][5] += c2.y; vsum[jb][6] += c2.z; vsum[jb][7] += c2.w;
            }
        }
    }

    float sacc[NJB][8];
    #pragma unroll
    for (int jb = 0; jb < NJB; jb++)
        #pragma unroll
        for (int h2 = 0; h2 < 8; h2++) sacc[jb][h2] = 0.f;

    // u double buffer; prologue load for ii = 0 (broadcast: wave shares bq).
    float us[2][NJB][8];
    #pragma unroll
    for (int jb = 0; jb < NJB; jb++) {
        const float* ub = u + ((size_t)(bbase + bq * NJB + jb) * II + i0) * DD;
        float4 a = *(const float4*)ub;
        float4 c = *(const float4*)(ub + 4);
        us[0][jb][0] = a.x; us[0][jb][1] = a.y; us[0][jb][2] = a.z; us[0][jb][3] = a.w;
        us[0][jb][4] = c.x; us[0][jb][5] = c.y; us[0][jb][6] = c.z; us[0][jb][7] = c.w;
    }

    __syncthreads();   // barrier drains vmcnt(0): Wsh[0] DMA complete

    #pragma unroll     // full unroll: IC=9 -> buffer indices are compile-time
    for (int ii = 0; ii < IC; ii++) {
        const float* wcur = Wsh[ii & 1];
        const int cur = ii & 1, nxt = cur ^ 1;

        // Issue next tile's DMA first; it has the whole compute phase to land.
        if (ii + 1 < IC)
            stage_w_tile(w + (size_t)(i0 + ii + 1) * WTILE, Wsh[nxt], tid);

        // Prefetch u[i+1] (cold lines, ~one latency hidden under compute).
        if (ii + 1 < IC) {
            #pragma unroll
            for (int jb = 0; jb < NJB; jb++) {
                const float* ub = u + ((size_t)(bbase + bq * NJB + jb) * II + (i0 + ii + 1)) * DD;
                float4 a = *(const float4*)ub;
                float4 c = *(const float4*)(ub + 4);
                us[nxt][jb][0] = a.x; us[nxt][jb][1] = a.y; us[nxt][jb][2] = a.z; us[nxt][jb][3] = a.w;
                us[nxt][jb][4] = c.x; us[nxt][jb][5] = c.y; us[nxt][jb][6] = c.z; us[nxt][jb][7] = c.w;
            }
        }

        // u_hat[b, i, o, h-half] = sum_d u[b,i,d] * W[i,o,d,h]
        float uh[NJB][8];
        #pragma unroll
        for (int jb = 0; jb < NJB; jb++)
            #pragma unroll
            for (int h2 = 0; h2 < 8; h2++) uh[jb][h2] = 0.f;
        #pragma unroll
        for (int d = 0; d < DD; d++) {
            const int ba = (d * HH + hofs    ) ^ swm;   // swizzled read offsets
            const int bb = (d * HH + hofs + 4) ^ swm;
            float4 wa = *(const float4*)&wcur[orow + ba];
            float4 wb = *(const float4*)&wcur[orow + bb];
            const float wv[8] = {wa.x, wa.y, wa.z, wa.w, wb.x, wb.y, wb.z, wb.w};
            #pragma unroll
            for (int jb = 0; jb < NJB; jb++)
                #pragma unroll
                for (int h2 = 0; h2 < 8; h2++)
                    uh[jb][h2] = fmaf(us[cur][jb][d], wv[h2], uh[jb][h2]);
        }

        // coupling: softmax over o of (vsum . u_hat); PASS 0 -> uniform 1/32
        float cc[NJB];
        if (PASS == 0) {
            #pragma unroll
            for (int jb = 0; jb < NJB; jb++) cc[jb] = 1.0f / 32.0f;
        } else {
            #pragma unroll
            for (int jb = 0; jb < NJB; jb++) {
                float lg = 0.f;
                #pragma unroll
                for (int h2 = 0; h2 < 8; h2++)
                    lg = fmaf(vsum[jb][h2], uh[jb][h2], lg);
                lg = add_xor32(lg);                // h-half combine (VALU)
                const float e = __expf(lg);        // |lg| small -> no max-sub
                const float se = add_xor16(row_sum16(e));  // sum over 32 o-lanes (VALU)
                cc[jb] = __fdividef(e, se);
            }
        }

        #pragma unroll
        for (int jb = 0; jb < NJB; jb++)
            #pragma unroll
            for (int h2 = 0; h2 < 8; h2++)
                sacc[jb][h2] = fmaf(cc[jb], uh[jb][h2], sacc[jb][h2]);

        // barrier drains vmcnt (next tile's DMA + u prefetch) + lgkmcnt
        __syncthreads();
    }

    // emit partial s
    #pragma unroll
    for (int jb = 0; jb < NJB; jb++) {
        const int b = bbase + bq * NJB + jb;
        if (ATOMIC) {
            float* p = out + ((b * OO + o) * HH + hofs);
            #pragma unroll
            for (int h2 = 0; h2 < 8; h2++) atomicAdd(p + h2, sacc[jb][h2]);
        } else {
            // per-chunk slab: fully-covered contiguous lines
            float* p = out + ((size_t)blockIdx.x * BB + b) * (OO * HH) + o * HH + hofs;
            *(float4*)p       = make_float4(sacc[jb][0], sacc[jb][1], sacc[jb][2], sacc[jb][3]);
            *(float4*)(p + 4) = make_float4(sacc[jb][4], sacc[jb][5], sacc[jb][6], sacc[jb][7]);
        }
    }
}

// ---------------------------------------------------------------------------
// Fused reduce-over-chunks + squash, wide version (R2): 256 blocks so the
// 16.8 MB partial read spreads over the whole chip (R1's 32 blocks left
// 87% of CUs idle -> ~20 us; this is a ~3-4 us dispatch).
// Block handles 32 consecutive float4 elements (t4) of [b][o][h]; the 128
// chunks split 8-ways across thread groups (icp), LDS tree combines.
// ---------------------------------------------------------------------------
__global__ __launch_bounds__(256)
void reduce_squash_wide_kernel(const float* __restrict__ part, float* __restrict__ v)
{
    const int t4l = threadIdx.x & 31;          // 0..31: which t4 in the block
    const int icp = threadIdx.x >> 5;          // 0..7: which chunk-octant
    const int t4  = blockIdx.x * 32 + t4l;     // 0..BOH/4-1

    const float4* p = (const float4*)part + t4;
    float4 acc = make_float4(0.f, 0.f, 0.f, 0.f);
    #pragma unroll
    for (int k = 0; k < 16; k++) {
        float4 x = p[(size_t)(icp * 16 + k) * (BOH / 4)];
        acc.x += x.x; acc.y += x.y; acc.z += x.z; acc.w += x.w;
    }

    __shared__ float4 red[8][32];
    red[icp][t4l] = acc;
    __syncthreads();

    if (threadIdx.x < 32) {
        float4 a = red[0][t4l];
        #pragma unroll
        for (int j = 1; j < 8; j++) {
            float4 x = red[j][t4l];
            a.x += x.x; a.y += x.y; a.z += x.z; a.w += x.w;
        }
        // squash over h: each (b,o) is 4 consecutive t4 -> quad_perm butterfly
        float sq = a.x * a.x + a.y * a.y + a.z * a.z + a.w * a.w;
        sq = dpp_add<0xB1>(sq);   // quad_perm [1,0,3,2]
        sq = dpp_add<0x4E>(sq);   // quad_perm [2,3,0,1]
        const float scale = (sq / (1.f + sq)) * rsqrtf(sq + 1e-8f);
        a.x *= scale; a.y *= scale; a.z *= scale; a.w *= scale;
        ((float4*)v)[t4] = a;
    }
}

// Standalone squash for the atomic tiny-ws fallback.
__global__ __launch_bounds__(256)
void squash_kernel(const float* __restrict__ s, float* __restrict__ v)
{
    const int t = blockIdx.x * blockDim.x + threadIdx.x;
    if (t >= BB * OO) return;
    const float4* sp = (const float4*)(s + t * HH);
    float4 a = sp[0], b = sp[1], c = sp[2], d = sp[3];
    float sq = a.x*a.x + a.y*a.y + a.z*a.z + a.w*a.w
             + b.x*b.x + b.y*b.y + b.z*b.z + b.w*b.w
             + c.x*c.x + c.y*c.y + c.z*c.z + c.w*c.w
             + d.x*d.x + d.y*d.y + d.z*d.z + d.w*d.w;
    const float scale = (sq / (1.f + sq)) * rsqrtf(sq + 1e-8f);
    a.x *= scale; a.y *= scale; a.z *= scale; a.w *= scale;
    b.x *= scale; b.y *= scale; b.z *= scale; b.w *= scale;
    c.x *= scale; c.y *= scale; c.z *= scale; c.w *= scale;
    d.x *= scale; d.y *= scale; d.z *= scale; d.w *= scale;
    float4* vp = (float4*)(v + t * HH);
    vp[0] = a; vp[1] = b; vp[2] = c; vp[3] = d;
}

extern "C" void kernel_launch(void* const* d_in, const int* in_sizes, int n_in,
                              void* d_out, int out_size, void* d_ws, size_t ws_size,
                              hipStream_t stream)
{
    (void)in_sizes; (void)n_in; (void)out_size;
    const float* u = (const float*)d_in[0];
    const float* w = (const float*)d_in[1];
    float* out = (float*)d_out;

    const size_t need = ((size_t)NIC * BOH + 2 * BOH) * sizeof(float);  // ~16.3 MB
    const dim3 grid(NIC, NBG), blk(256);

    if (ws_size >= need) {
        // 6 dispatches; kernel boundaries are the (cheap) grid barrier.
        float* part = (float*)d_ws;                 // NIC x BOH partial s
        float* v0   = part + (size_t)NIC * BOH;
        float* v1   = v0 + BOH;
        const int rblocks = BOH / 4 / 32;           // 256 blocks

        pass_kernel<0, false><<<grid, blk, 0, stream>>>(u, w, nullptr, nullptr, part);
        reduce_squash_wide_kernel<<<rblocks, 256, 0, stream>>>(part, v0);
        pass_kernel<1, false><<<grid, blk, 0, stream>>>(u, w, v0, nullptr, part);
        reduce_squash_wide_kernel<<<rblocks, 256, 0, stream>>>(part, v1);
        pass_kernel<2, false><<<grid, blk, 0, stream>>>(u, w, v0, v1, part);
        reduce_squash_wide_kernel<<<rblocks, 256, 0, stream>>>(part, out);
    } else {
        // Tiny-ws fallback: atomic path.
        float* s0 = (float*)d_ws;
        float* s1 = s0 + BOH;
        float* v0 = s1 + BOH;
        float* v1 = v0 + BOH;
        hipMemsetAsync(d_ws, 0, 2 * BOH * sizeof(float), stream);
        hipMemsetAsync(d_out, 0, BOH * sizeof(float), stream);
        const int sq_blocks = (BB * OO + 255) / 256;

        pass_kernel<0, true><<<grid, blk, 0, stream>>>(u, w, nullptr, nullptr, s0);
        squash_kernel<<<sq_blocks, 256, 0, stream>>>(s0, v0);
        pass_kernel<1, true><<<grid, blk, 0, stream>>>(u, w, v0, nullptr, s1);
        squash_kernel<<<sq_blocks, 256, 0, stream>>>(s1, v1);
        pass_kernel<2, true><<<grid, blk, 0, stream>>>(u, w, v0, v1, out);
        squash_kernel<<<sq_blocks, 256, 0, stream>>>(out, out);
    }
}

// Round 3
// 178.742 us; speedup vs baseline: 4.7727x; 4.7727x over previous
//
#include <hip/hip_runtime.h>

// Problem constants
#define BB 64
#define II 1152
#define OO 32
#define DD 8
#define HH 16
#define BOH (BB * OO * HH)    // 32768
#define WTILE (OO * DD * HH)  // 4096 floats per i

// Decomposition: NIC * IC == II. R3: IC=3 so a block stages ALL its W tiles
// up-front (48 KB LDS), runs barrier-free, and the chip holds 3 blocks/CU.
#define IC   3
#define NIC  384
#define NBB  16    // b per block
#define NBG  4     // b-groups (NBG * NBB == BB)
#define NJB  4     // b per thread

// ---------------------------------------------------------------------------
// DPP add helper (ctrl must be an ICE -> template param).
// ---------------------------------------------------------------------------
template<int CTRL>
__device__ __forceinline__ float dpp_add(float x)
{
    return x + __int_as_float(__builtin_amdgcn_update_dpp(
            0, __float_as_int(x), CTRL, 0xF, 0xF, false));
}

// Sum over each 16-lane row, result in every lane of the row (VALU only).
__device__ __forceinline__ float row_sum16(float x)
{
    x = dpp_add<0x121>(x);   // row_ror:1
    x = dpp_add<0x122>(x);   // row_ror:2
    x = dpp_add<0x124>(x);   // row_ror:4
    x = dpp_add<0x128>(x);   // row_ror:8
    return x;
}

// lane l gets x[l] + x[l^32] — v_permlane32_swap keeps this on the VALU pipe.
__device__ __forceinline__ float add_xor32(float x)
{
#if __has_builtin(__builtin_amdgcn_permlane32_swap)
    auto r = __builtin_amdgcn_permlane32_swap(
        __float_as_uint(x), __float_as_uint(x), false, false);
    return __uint_as_float(r[0]) + __uint_as_float(r[1]);
#else
    return x + __shfl_xor(x, 32, 64);
#endif
}

// lane l gets x[l] + x[l^16] — VALU permlane16_swap vs DS-pipe ds_swizzle.
__device__ __forceinline__ float add_xor16(float x)
{
#if __has_builtin(__builtin_amdgcn_permlane16_swap)
    auto r = __builtin_amdgcn_permlane16_swap(
        __float_as_uint(x), __float_as_uint(x), false, false);
    return __uint_as_float(r[0]) + __uint_as_float(r[1]);
#else
    return x + __int_as_float(__builtin_amdgcn_ds_swizzle(__float_as_int(x), 0x401F));
#endif
}

// ---------------------------------------------------------------------------
// 5-bit XOR swizzle on a float index within one 4096-float W tile.
// f = o*128 + d*16 + h. XOR float bits [6:2] with o (bits [11:7]) — an
// involution that keeps 16-B groups contiguous. Read-side: the 64 lanes'
// ds_read_b128 chunk-starts (4o ^ 8hh patterns) cover all 32 16-B slots of
// a 512-B row with multiplicity exactly 2 -> conflict-free (2-way is free,
// m136). R2's 3-bit version left a 4-way conflict (1.18M/dispatch).
// ---------------------------------------------------------------------------
__device__ __forceinline__ int wswz(int f) { return f ^ (((f >> 7) & 31) << 2); }

// Stage one 16 KB W tile global->LDS via DMA (linear LDS dest, pre-swizzled
// global source; both-sides-same-involution rule).
__device__ __forceinline__ void stage_w_tile(const float* __restrict__ wg,
                                             float* __restrict__ wn, int tid)
{
    #pragma unroll
    for (int j = 0; j < 4; j++) {
        const int P = (tid + j * 256) * 4;    // linear LDS float index
        const int g = wswz(P);                // pre-swizzled global source
        __builtin_amdgcn_global_load_lds(
            (const __attribute__((address_space(1))) void*)(wg + g),
            (__attribute__((address_space(3))) void*)(wn + P),
            16, 0, 0);
    }
}

// ---------------------------------------------------------------------------
// Pass kernel: one routing iteration. Grid (NIC, NBG) = 1536 blocks x 256 thr.
// tid = o + 32*hh + 64*bq. Logits are linear in v, so vsum (= v0 [+ v1])
// replaces any logits array; PASS 0 has uniform coupling 1/32.
// R3 structure: stage all IC=3 tiles up-front -> ONE barrier per block, then
// barrier-free compute (LDS is read-only). 48 KB LDS -> 3 blocks/CU resident;
// the next block's DMA overlaps this block's compute (block-level pipelining).
// ---------------------------------------------------------------------------
template<int PASS, bool ATOMIC>
__global__ __launch_bounds__(256)
void pass_kernel(const float* __restrict__ u, const float* __restrict__ w,
                 const float* __restrict__ pv0, const float* __restrict__ pv1,
                 float* __restrict__ out)
{
    __shared__ __align__(16) float Wsh[IC][WTILE];   // 3 x 16 KB, linear

    const int tid   = threadIdx.x;
    const int o     = tid & 31;
    const int hh    = (tid >> 5) & 1;
    const int bq    = tid >> 6;           // 0..3
    const int bbase = blockIdx.y * NBB;
    const int i0    = blockIdx.x * IC;
    const int hofs  = hh * 8;
    const int swm   = o << 2;             // read-side XOR (floats), 5-bit
    const int orow  = o * (DD * HH);

    // Kick off DMA for all 3 tiles immediately (overlaps vsum loads below).
    #pragma unroll
    for (int t = 0; t < IC; t++)
        stage_w_tile(w + (size_t)(i0 + t) * WTILE, Wsh[t], tid);

    // vsum = sum of previous v's (constant over i).
    float vsum[NJB][8];
    if (PASS >= 1) {
        #pragma unroll
        for (int jb = 0; jb < NJB; jb++) {
            const int b = bbase + bq * NJB + jb;
            const float* p = pv0 + ((b * OO + o) * HH + hofs);
            float4 a = *(const float4*)p;
            float4 c = *(const float4*)(p + 4);
            vsum[jb][0] = a.x; vsum[jb][1] = a.y; vsum[jb][2] = a.z; vsum[jb][3] = a.w;
            vsum[jb][4] = c.x; vsum[jb][5] = c.y; vsum[jb][6] = c.z; vsum[jb][7] = c.w;
            if (PASS == 2) {
                const float* q = pv1 + ((b * OO + o) * HH + hofs);
                float4 a2 = *(const float4*)q;
                float4 c2 = *(const float4*)(q + 4);
                vsum[jb][0] += a2.x; vsum[jb][1] += a2.y; vsum[jb][2] += a2.z; vsum[jb][3] += a2.w;
                vsum[jb][4] += c2.x; vsum[jb][5] += c2.y; vsum[jb][6] += c2.z; vsum[jb][7] += c2.w;
            }
        }
    }

    float sacc[NJB][8];
    #pragma unroll
    for (int jb = 0; jb < NJB; jb++)
        #pragma unroll
        for (int h2 = 0; h2 < 8; h2++) sacc[jb][h2] = 0.f;

    __syncthreads();   // drains vmcnt(0): all 3 tile DMAs complete. ONLY barrier.

    #pragma unroll
    for (int ii = 0; ii < IC; ii++) {
        const float* wcur = Wsh[ii];

        // u via broadcast global loads: whole wave shares bq -> same address.
        float us[NJB][8];
        #pragma unroll
        for (int jb = 0; jb < NJB; jb++) {
            const float* ub = u + ((size_t)(bbase + bq * NJB + jb) * II + (i0 + ii)) * DD;
            float4 a = *(const float4*)ub;
            float4 c = *(const float4*)(ub + 4);
            us[jb][0] = a.x; us[jb][1] = a.y; us[jb][2] = a.z; us[jb][3] = a.w;
            us[jb][4] = c.x; us[jb][5] = c.y; us[jb][6] = c.z; us[jb][7] = c.w;
        }

        // u_hat[b, i, o, h-half] = sum_d u[b,i,d] * W[i,o,d,h]
        float uh[NJB][8];
        #pragma unroll
        for (int jb = 0; jb < NJB; jb++)
            #pragma unroll
            for (int h2 = 0; h2 < 8; h2++) uh[jb][h2] = 0.f;
        #pragma unroll
        for (int d = 0; d < DD; d++) {
            const int ba = (d * HH + hofs    ) ^ swm;   // swizzled read offsets
            const int bb = (d * HH + hofs + 4) ^ swm;
            float4 wa = *(const float4*)&wcur[orow + ba];
            float4 wb = *(const float4*)&wcur[orow + bb];
            const float wv[8] = {wa.x, wa.y, wa.z, wa.w, wb.x, wb.y, wb.z, wb.w};
            #pragma unroll
            for (int jb = 0; jb < NJB; jb++)
                #pragma unroll
                for (int h2 = 0; h2 < 8; h2++)
                    uh[jb][h2] = fmaf(us[jb][d], wv[h2], uh[jb][h2]);
        }

        // coupling: softmax over o of (vsum . u_hat); PASS 0 -> uniform 1/32
        float cc[NJB];
        if (PASS == 0) {
            #pragma unroll
            for (int jb = 0; jb < NJB; jb++) cc[jb] = 1.0f / 32.0f;
        } else {
            #pragma unroll
            for (int jb = 0; jb < NJB; jb++) {
                float lg = 0.f;
                #pragma unroll
                for (int h2 = 0; h2 < 8; h2++)
                    lg = fmaf(vsum[jb][h2], uh[jb][h2], lg);
                lg = add_xor32(lg);                // h-half combine (VALU)
                const float e = __expf(lg);        // |lg| small -> no max-sub
                const float se = add_xor16(row_sum16(e));  // sum over 32 o-lanes (VALU)
                cc[jb] = __fdividef(e, se);
            }
        }

        #pragma unroll
        for (int jb = 0; jb < NJB; jb++)
            #pragma unroll
            for (int h2 = 0; h2 < 8; h2++)
                sacc[jb][h2] = fmaf(cc[jb], uh[jb][h2], sacc[jb][h2]);
        // no barrier: LDS read-only after the single up-front stage
    }

    // emit partial s
    #pragma unroll
    for (int jb = 0; jb < NJB; jb++) {
        const int b = bbase + bq * NJB + jb;
        if (ATOMIC) {
            float* p = out + ((b * OO + o) * HH + hofs);
            #pragma unroll
            for (int h2 = 0; h2 < 8; h2++) atomicAdd(p + h2, sacc[jb][h2]);
        } else {
            // per-chunk slab: fully-covered contiguous lines
            float* p = out + ((size_t)blockIdx.x * BB + b) * (OO * HH) + o * HH + hofs;
            *(float4*)p       = make_float4(sacc[jb][0], sacc[jb][1], sacc[jb][2], sacc[jb][3]);
            *(float4*)(p + 4) = make_float4(sacc[jb][4], sacc[jb][5], sacc[jb][6], sacc[jb][7]);
        }
    }
}

// ---------------------------------------------------------------------------
// Fused reduce-over-chunks + squash, wide version: 256 blocks so the 50 MB
// partial read spreads over the whole chip. Block handles 32 consecutive
// float4 elements (t4) of [b][o][h]; the 384 chunks split 8-ways across
// thread groups (icp, 48 each), LDS tree combines.
// ---------------------------------------------------------------------------
__global__ __launch_bounds__(256)
void reduce_squash_wide_kernel(const float* __restrict__ part, float* __restrict__ v)
{
    const int t4l = threadIdx.x & 31;          // 0..31: which t4 in the block
    const int icp = threadIdx.x >> 5;          // 0..7: which chunk-octant
    const int t4  = blockIdx.x * 32 + t4l;     // 0..BOH/4-1

    const float4* p = (const float4*)part + t4;
    float4 acc = make_float4(0.f, 0.f, 0.f, 0.f);
    #pragma unroll 8
    for (int k = 0; k < NIC / 8; k++) {
        float4 x = p[(size_t)(icp * (NIC / 8) + k) * (BOH / 4)];
        acc.x += x.x; acc.y += x.y; acc.z += x.z; acc.w += x.w;
    }

    __shared__ float4 red[8][32];
    red[icp][t4l] = acc;
    __syncthreads();

    if (threadIdx.x < 32) {
        float4 a = red[0][t4l];
        #pragma unroll
        for (int j = 1; j < 8; j++) {
            float4 x = red[j][t4l];
            a.x += x.x; a.y += x.y; a.z += x.z; a.w += x.w;
        }
        // squash over h: each (b,o) is 4 consecutive t4 -> quad_perm butterfly
        float sq = a.x * a.x + a.y * a.y + a.z * a.z + a.w * a.w;
        sq = dpp_add<0xB1>(sq);   // quad_perm [1,0,3,2]
        sq = dpp_add<0x4E>(sq);   // quad_perm [2,3,0,1]
        const float scale = (sq / (1.f + sq)) * rsqrtf(sq + 1e-8f);
        a.x *= scale; a.y *= scale; a.z *= scale; a.w *= scale;
        ((float4*)v)[t4] = a;
    }
}

// Standalone squash for the atomic tiny-ws fallback.
__global__ __launch_bounds__(256)
void squash_kernel(const float* __restrict__ s, float* __restrict__ v)
{
    const int t = blockIdx.x * blockDim.x + threadIdx.x;
    if (t >= BB * OO) return;
    const float4* sp = (const float4*)(s + t * HH);
    float4 a = sp[0], b = sp[1], c = sp[2], d = sp[3];
    float sq = a.x*a.x + a.y*a.y + a.z*a.z + a.w*a.w
             + b.x*b.x + b.y*b.y + b.z*b.z + b.w*b.w
             + c.x*c.x + c.y*c.y + c.z*c.z + c.w*c.w
             + d.x*d.x + d.y*d.y + d.z*d.z + d.w*d.w;
    const float scale = (sq / (1.f + sq)) * rsqrtf(sq + 1e-8f);
    a.x *= scale; a.y *= scale; a.z *= scale; a.w *= scale;
    b.x *= scale; b.y *= scale; b.z *= scale; b.w *= scale;
    c.x *= scale; c.y *= scale; c.z *= scale; c.w *= scale;
    d.x *= scale; d.y *= scale; d.z *= scale; d.w *= scale;
    float4* vp = (float4*)(v + t * HH);
    vp[0] = a; vp[1] = b; vp[2] = c; vp[3] = d;
}

extern "C" void kernel_launch(void* const* d_in, const int* in_sizes, int n_in,
                              void* d_out, int out_size, void* d_ws, size_t ws_size,
                              hipStream_t stream)
{
    (void)in_sizes; (void)n_in; (void)out_size;
    const float* u = (const float*)d_in[0];
    const float* w = (const float*)d_in[1];
    float* out = (float*)d_out;

    const size_t need = ((size_t)NIC * BOH + 2 * BOH) * sizeof(float);  // ~50.6 MB
    const dim3 grid(NIC, NBG), blk(256);

    if (ws_size >= need) {
        // 6 dispatches; kernel boundaries are the (cheap) grid barrier.
        float* part = (float*)d_ws;                 // NIC x BOH partial s
        float* v0   = part + (size_t)NIC * BOH;
        float* v1   = v0 + BOH;
        const int rblocks = BOH / 4 / 32;           // 256 blocks

        pass_kernel<0, false><<<grid, blk, 0, stream>>>(u, w, nullptr, nullptr, part);
        reduce_squash_wide_kernel<<<rblocks, 256, 0, stream>>>(part, v0);
        pass_kernel<1, false><<<grid, blk, 0, stream>>>(u, w, v0, nullptr, part);
        reduce_squash_wide_kernel<<<rblocks, 256, 0, stream>>>(part, v1);
        pass_kernel<2, false><<<grid, blk, 0, stream>>>(u, w, v0, v1, part);
        reduce_squash_wide_kernel<<<rblocks, 256, 0, stream>>>(part, out);
    } else {
        // Tiny-ws fallback: atomic path.
        float* s0 = (float*)d_ws;
        float* s1 = s0 + BOH;
        float* v0 = s1 + BOH;
        float* v1 = v0 + BOH;
        hipMemsetAsync(d_ws, 0, 2 * BOH * sizeof(float), stream);
        hipMemsetAsync(d_out, 0, BOH * sizeof(float), stream);
        const int sq_blocks = (BB * OO + 255) / 256;

        pass_kernel<0, true><<<grid, blk, 0, stream>>>(u, w, nullptr, nullptr, s0);
        squash_kernel<<<sq_blocks, 256, 0, stream>>>(s0, v0);
        pass_kernel<1, true><<<grid, blk, 0, stream>>>(u, w, v0, nullptr, s1);
        squash_kernel<<<sq_blocks, 256, 0, stream>>>(s1, v1);
        pass_kernel<2, true><<<grid, blk, 0, stream>>>(u, w, v0, v1, out);
        squash_kernel<<<sq_blocks, 256, 0, stream>>>(out, out);
    }
}

// Round 4
// 138.394 us; speedup vs baseline: 6.1642x; 1.2915x over previous
//
#include <hip/hip_runtime.h>

// Problem constants
#define BB 64
#define II 1152
#define OO 32
#define DD 8
#define HH 16
#define BOH (BB * OO * HH)    // 32768
#define WTILE (OO * DD * HH)  // 4096 floats per i

// Decomposition: NIC * IC == II. R4: back to IC=9/NIC=128 (16.8 MB partials —
// R3's NIC=384 added +100 MB/iter of workspace traffic = +32 us). Grid is
// (NIC, NBG) = 1024 blocks -> 4 blocks/CU so inter-block overlap hides the
// per-iteration staging drain (R1's 512 blocks = 2/CU was latency-bound).
#define IC   9
#define NIC  128
#define NBB  8     // b per block
#define NBG  8     // b-groups (NBG * NBB == BB)
#define NJB  2     // b per thread

// ---------------------------------------------------------------------------
// DPP add helper (ctrl must be an ICE -> template param).
// ---------------------------------------------------------------------------
template<int CTRL>
__device__ __forceinline__ float dpp_add(float x)
{
    return x + __int_as_float(__builtin_amdgcn_update_dpp(
            0, __float_as_int(x), CTRL, 0xF, 0xF, false));
}

// Sum over each 16-lane row, result in every lane of the row (VALU only).
__device__ __forceinline__ float row_sum16(float x)
{
    x = dpp_add<0x121>(x);   // row_ror:1
    x = dpp_add<0x122>(x);   // row_ror:2
    x = dpp_add<0x124>(x);   // row_ror:4
    x = dpp_add<0x128>(x);   // row_ror:8
    return x;
}

// lane l gets x[l] + x[l^32] — v_permlane32_swap keeps this on the VALU pipe.
__device__ __forceinline__ float add_xor32(float x)
{
#if __has_builtin(__builtin_amdgcn_permlane32_swap)
    auto r = __builtin_amdgcn_permlane32_swap(
        __float_as_uint(x), __float_as_uint(x), false, false);
    return __uint_as_float(r[0]) + __uint_as_float(r[1]);
#else
    return x + __shfl_xor(x, 32, 64);
#endif
}

// lane l gets x[l] + x[l^16] — VALU permlane16_swap vs DS-pipe ds_swizzle.
__device__ __forceinline__ float add_xor16(float x)
{
#if __has_builtin(__builtin_amdgcn_permlane16_swap)
    auto r = __builtin_amdgcn_permlane16_swap(
        __float_as_uint(x), __float_as_uint(x), false, false);
    return __uint_as_float(r[0]) + __uint_as_float(r[1]);
#else
    return x + __int_as_float(__builtin_amdgcn_ds_swizzle(__float_as_int(x), 0x401F));
#endif
}

// ---------------------------------------------------------------------------
// 5-bit XOR swizzle on a float index within one 4096-float W tile.
// f = o*128 + d*16 + h. XOR float bits [6:2] with o (bits [11:7]) — an
// involution that keeps 16-B groups contiguous. Read-side bank histogram for
// the wave's 64 ds_read_b128: 256 dword-accesses spread exactly 8 per bank
// (uniform) -> conflict-free floor. (R2's 3-bit version left 4-way.)
// ---------------------------------------------------------------------------
__device__ __forceinline__ int wswz(int f) { return f ^ (((f >> 7) & 31) << 2); }

// Stage one 16 KB W tile global->LDS via DMA (linear LDS dest, pre-swizzled
// global source; both-sides-same-involution rule).
__device__ __forceinline__ void stage_w_tile(const float* __restrict__ wg,
                                             float* __restrict__ wn, int tid)
{
    #pragma unroll
    for (int j = 0; j < 4; j++) {
        const int P = (tid + j * 256) * 4;    // linear LDS float index
        const int g = wswz(P);                // pre-swizzled global source
        __builtin_amdgcn_global_load_lds(
            (const __attribute__((address_space(1))) void*)(wg + g),
            (__attribute__((address_space(3))) void*)(wn + P),
            16, 0, 0);
    }
}

// ---------------------------------------------------------------------------
// Pass kernel: one routing iteration. Grid (NIC, NBG) = 1024 blocks x 256 thr.
// tid = o + 32*hh + 64*bq. Logits are linear in v, so vsum (= v0 [+ v1])
// replaces any logits array; PASS 0 has uniform coupling 1/32.
// Per iteration: stage W[i+1] by DMA into the other buffer, broadcast-load u,
// 2x8 FMA block, pure-VALU softmax, accumulate; one barrier (drains the DMA).
// 4 blocks/CU make the drain overlap other blocks' compute.
// ---------------------------------------------------------------------------
template<int PASS, bool ATOMIC>
__global__ __launch_bounds__(256)
void pass_kernel(const float* __restrict__ u, const float* __restrict__ w,
                 const float* __restrict__ pv0, const float* __restrict__ pv1,
                 float* __restrict__ out)
{
    __shared__ __align__(16) float Wsh[2][WTILE];   // 2 x 16 KB, linear

    const int tid   = threadIdx.x;
    const int o     = tid & 31;
    const int hh    = (tid >> 5) & 1;
    const int bq    = tid >> 6;           // 0..3
    const int bbase = blockIdx.y * NBB;
    const int i0    = blockIdx.x * IC;
    const int hofs  = hh * 8;
    const int swm   = o << 2;             // read-side XOR (floats), 5-bit
    const int orow  = o * (DD * HH);

    // Kick off DMA for W[i0] immediately (overlaps vsum loads below).
    stage_w_tile(w + (size_t)i0 * WTILE, Wsh[0], tid);

    // vsum = sum of previous v's (constant over i).
    float vsum[NJB][8];
    if (PASS >= 1) {
        #pragma unroll
        for (int jb = 0; jb < NJB; jb++) {
            const int b = bbase + bq * NJB + jb;
            const float* p = pv0 + ((b * OO + o) * HH + hofs);
            float4 a = *(const float4*)p;
            float4 c = *(const float4*)(p + 4);
            vsum[jb][0] = a.x; vsum[jb][1] = a.y; vsum[jb][2] = a.z; vsum[jb][3] = a.w;
            vsum[jb][4] = c.x; vsum[jb][5] = c.y; vsum[jb][6] = c.z; vsum[jb][7] = c.w;
            if (PASS == 2) {
                const float* q = pv1 + ((b * OO + o) * HH + hofs);
                float4 a2 = *(const float4*)q;
                float4 c2 = *(const float4*)(q + 4);
                vsum[jb][0] += a2.x; vsum[jb][1] += a2.y; vsum[jb][2] += a2.z; vsum[jb][3] += a2.w;
                vsum[jb][4] += c2.x; vsum[jb][5] += c2.y; vsum[jb][6] += c2.z; vsum[jb][7] += c2.w;
            }
        }
    }

    float sacc[NJB][8];
    #pragma unroll
    for (int jb = 0; jb < NJB; jb++)
        #pragma unroll
        for (int h2 = 0; h2 < 8; h2++) sacc[jb][h2] = 0.f;

    __syncthreads();   // drains vmcnt(0): Wsh[0] DMA complete

    for (int ii = 0; ii < IC; ii++) {
        const float* wcur = Wsh[ii & 1];

        // Issue next tile's DMA first; it has the whole compute phase to land.
        if (ii + 1 < IC)
            stage_w_tile(w + (size_t)(i0 + ii + 1) * WTILE, Wsh[(ii + 1) & 1], tid);

        // u via broadcast global loads: whole wave shares bq -> same address
        // (L1 broadcast; u slice is L2-hot, re-read by the 8 y-sibling blocks).
        float us[NJB][8];
        #pragma unroll
        for (int jb = 0; jb < NJB; jb++) {
            const float* ub = u + ((size_t)(bbase + bq * NJB + jb) * II + (i0 + ii)) * DD;
            float4 a = *(const float4*)ub;
            float4 c = *(const float4*)(ub + 4);
            us[jb][0] = a.x; us[jb][1] = a.y; us[jb][2] = a.z; us[jb][3] = a.w;
            us[jb][4] = c.x; us[jb][5] = c.y; us[jb][6] = c.z; us[jb][7] = c.w;
        }

        // u_hat[b, i, o, h-half] = sum_d u[b,i,d] * W[i,o,d,h]
        float uh[NJB][8];
        #pragma unroll
        for (int jb = 0; jb < NJB; jb++)
            #pragma unroll
            for (int h2 = 0; h2 < 8; h2++) uh[jb][h2] = 0.f;
        #pragma unroll
        for (int d = 0; d < DD; d++) {
            const int ba = (d * HH + hofs    ) ^ swm;   // swizzled read offsets
            const int bb = (d * HH + hofs + 4) ^ swm;
            float4 wa = *(const float4*)&wcur[orow + ba];
            float4 wb = *(const float4*)&wcur[orow + bb];
            const float wv[8] = {wa.x, wa.y, wa.z, wa.w, wb.x, wb.y, wb.z, wb.w};
            #pragma unroll
            for (int jb = 0; jb < NJB; jb++)
                #pragma unroll
                for (int h2 = 0; h2 < 8; h2++)
                    uh[jb][h2] = fmaf(us[jb][d], wv[h2], uh[jb][h2]);
        }

        // coupling: softmax over o of (vsum . u_hat); PASS 0 -> uniform 1/32
        float cc[NJB];
        if (PASS == 0) {
            #pragma unroll
            for (int jb = 0; jb < NJB; jb++) cc[jb] = 1.0f / 32.0f;
        } else {
            #pragma unroll
            for (int jb = 0; jb < NJB; jb++) {
                float lg = 0.f;
                #pragma unroll
                for (int h2 = 0; h2 < 8; h2++)
                    lg = fmaf(vsum[jb][h2], uh[jb][h2], lg);
                lg = add_xor32(lg);                // h-half combine (VALU)
                const float e = __expf(lg);        // |lg| small -> no max-sub
                const float se = add_xor16(row_sum16(e));  // sum over 32 o-lanes (VALU)
                cc[jb] = __fdividef(e, se);
            }
        }

        #pragma unroll
        for (int jb = 0; jb < NJB; jb++)
            #pragma unroll
            for (int h2 = 0; h2 < 8; h2++)
                sacc[jb][h2] = fmaf(cc[jb], uh[jb][h2], sacc[jb][h2]);

        // barrier drains vmcnt (next tile's DMA) + lgkmcnt (our LDS reads)
        __syncthreads();
    }

    // emit partial s
    #pragma unroll
    for (int jb = 0; jb < NJB; jb++) {
        const int b = bbase + bq * NJB + jb;
        if (ATOMIC) {
            float* p = out + ((b * OO + o) * HH + hofs);
            #pragma unroll
            for (int h2 = 0; h2 < 8; h2++) atomicAdd(p + h2, sacc[jb][h2]);
        } else {
            // per-chunk slab: fully-covered contiguous lines
            float* p = out + ((size_t)blockIdx.x * BB + b) * (OO * HH) + o * HH + hofs;
            *(float4*)p       = make_float4(sacc[jb][0], sacc[jb][1], sacc[jb][2], sacc[jb][3]);
            *(float4*)(p + 4) = make_float4(sacc[jb][4], sacc[jb][5], sacc[jb][6], sacc[jb][7]);
        }
    }
}

// ---------------------------------------------------------------------------
// Fused reduce-over-chunks + squash, wide version: 256 blocks so the 16.8 MB
// partial read spreads over the whole chip (the 32-block R1 version left 87%
// of CUs idle -> ~18 us; this is ~5 us). Block handles 32 consecutive float4
// elements (t4) of [b][o][h]; the 128 chunks split 8-ways across thread
// groups (icp, 16 each), LDS tree combines.
// ---------------------------------------------------------------------------
__global__ __launch_bounds__(256)
void reduce_squash_wide_kernel(const float* __restrict__ part, float* __restrict__ v)
{
    const int t4l = threadIdx.x & 31;          // 0..31: which t4 in the block
    const int icp = threadIdx.x >> 5;          // 0..7: which chunk-octant
    const int t4  = blockIdx.x * 32 + t4l;     // 0..BOH/4-1

    const float4* p = (const float4*)part + t4;
    float4 acc = make_float4(0.f, 0.f, 0.f, 0.f);
    #pragma unroll
    for (int k = 0; k < NIC / 8; k++) {
        float4 x = p[(size_t)(icp * (NIC / 8) + k) * (BOH / 4)];
        acc.x += x.x; acc.y += x.y; acc.z += x.z; acc.w += x.w;
    }

    __shared__ float4 red[8][32];
    red[icp][t4l] = acc;
    __syncthreads();

    if (threadIdx.x < 32) {
        float4 a = red[0][t4l];
        #pragma unroll
        for (int j = 1; j < 8; j++) {
            float4 x = red[j][t4l];
            a.x += x.x; a.y += x.y; a.z += x.z; a.w += x.w;
        }
        // squash over h: each (b,o) is 4 consecutive t4 -> quad_perm butterfly
        float sq = a.x * a.x + a.y * a.y + a.z * a.z + a.w * a.w;
        sq = dpp_add<0xB1>(sq);   // quad_perm [1,0,3,2]
        sq = dpp_add<0x4E>(sq);   // quad_perm [2,3,0,1]
        const float scale = (sq / (1.f + sq)) * rsqrtf(sq + 1e-8f);
        a.x *= scale; a.y *= scale; a.z *= scale; a.w *= scale;
        ((float4*)v)[t4] = a;
    }
}

// Standalone squash for the atomic tiny-ws fallback.
__global__ __launch_bounds__(256)
void squash_kernel(const float* __restrict__ s, float* __restrict__ v)
{
    const int t = blockIdx.x * blockDim.x + threadIdx.x;
    if (t >= BB * OO) return;
    const float4* sp = (const float4*)(s + t * HH);
    float4 a = sp[0], b = sp[1], c = sp[2], d = sp[3];
    float sq = a.x*a.x + a.y*a.y + a.z*a.z + a.w*a.w
             + b.x*b.x + b.y*b.y + b.z*b.z + b.w*b.w
             + c.x*c.x + c.y*c.y + c.z*c.z + c.w*c.w
             + d.x*d.x + d.y*d.y + d.z*d.z + d.w*d.w;
    const float scale = (sq / (1.f + sq)) * rsqrtf(sq + 1e-8f);
    a.x *= scale; a.y *= scale; a.z *= scale; a.w *= scale;
    b.x *= scale; b.y *= scale; b.z *= scale; b.w *= scale;
    c.x *= scale; c.y *= scale; c.z *= scale; c.w *= scale;
    d.x *= scale; d.y *= scale; d.z *= scale; d.w *= scale;
    float4* vp = (float4*)(v + t * HH);
    vp[0] = a; vp[1] = b; vp[2] = c; vp[3] = d;
}

extern "C" void kernel_launch(void* const* d_in, const int* in_sizes, int n_in,
                              void* d_out, int out_size, void* d_ws, size_t ws_size,
                              hipStream_t stream)
{
    (void)in_sizes; (void)n_in; (void)out_size;
    const float* u = (const float*)d_in[0];
    const float* w = (const float*)d_in[1];
    float* out = (float*)d_out;

    const size_t need = ((size_t)NIC * BOH + 2 * BOH) * sizeof(float);  // ~17 MB
    const dim3 grid(NIC, NBG), blk(256);

    if (ws_size >= need) {
        // 6 dispatches; kernel boundaries are the (cheap) grid barrier.
        float* part = (float*)d_ws;                 // NIC x BOH partial s
        float* v0   = part + (size_t)NIC * BOH;
        float* v1   = v0 + BOH;
        const int rblocks = BOH / 4 / 32;           // 256 blocks

        pass_kernel<0, false><<<grid, blk, 0, stream>>>(u, w, nullptr, nullptr, part);
        reduce_squash_wide_kernel<<<rblocks, 256, 0, stream>>>(part, v0);
        pass_kernel<1, false><<<grid, blk, 0, stream>>>(u, w, v0, nullptr, part);
        reduce_squash_wide_kernel<<<rblocks, 256, 0, stream>>>(part, v1);
        pass_kernel<2, false><<<grid, blk, 0, stream>>>(u, w, v0, v1, part);
        reduce_squash_wide_kernel<<<rblocks, 256, 0, stream>>>(part, out);
    } else {
        // Tiny-ws fallback: atomic path.
        float* s0 = (float*)d_ws;
        float* s1 = s0 + BOH;
        float* v0 = s1 + BOH;
        float* v1 = v0 + BOH;
        hipMemsetAsync(d_ws, 0, 2 * BOH * sizeof(float), stream);
        hipMemsetAsync(d_out, 0, BOH * sizeof(float), stream);
        const int sq_blocks = (BB * OO + 255) / 256;

        pass_kernel<0, true><<<grid, blk, 0, stream>>>(u, w, nullptr, nullptr, s0);
        squash_kernel<<<sq_blocks, 256, 0, stream>>>(s0, v0);
        pass_kernel<1, true><<<grid, blk, 0, stream>>>(u, w, v0, nullptr, s1);
        squash_kernel<<<sq_blocks, 256, 0, stream>>>(s1, v1);
        pass_kernel<2, true><<<grid, blk, 0, stream>>>(u, w, v0, v1, out);
        squash_kernel<<<sq_blocks, 256, 0, stream>>>(out, out);
    }
}

// Round 5
// 137.113 us; speedup vs baseline: 6.2217x; 1.0093x over previous
//
#include <hip/hip_runtime.h>

// Problem constants
#define BB 64
#define II 1152
#define OO 32
#define DD 8
#define HH 16
#define BOH (BB * OO * HH)    // 32768
#define WTILE (OO * DD * HH)  // 4096 floats per i

// Decomposition: NIC * IC == II.
// R5: revert to R1's pass geometry — cross-round arithmetic showed R4's
// 1024-block/NJB=2 passes are ~11 us SLOWER each than R1's 512-block/NJB=4
// (per-thread amortization of staging+softmax+barrier beats occupancy here).
// Keep R4's wide reduce and the 5-bit conflict-free swizzle.
#define IC   9
#define NIC  128
#define NBB  16    // b per block
#define NBG  4     // b-groups (NBG * NBB == BB)
#define NJB  4     // b per thread

// ---------------------------------------------------------------------------
// DPP add helper (ctrl must be an ICE -> template param).
// ---------------------------------------------------------------------------
template<int CTRL>
__device__ __forceinline__ float dpp_add(float x)
{
    return x + __int_as_float(__builtin_amdgcn_update_dpp(
            0, __float_as_int(x), CTRL, 0xF, 0xF, false));
}

// Sum over each 16-lane row, result in every lane of the row (VALU only).
__device__ __forceinline__ float row_sum16(float x)
{
    x = dpp_add<0x121>(x);   // row_ror:1
    x = dpp_add<0x122>(x);   // row_ror:2
    x = dpp_add<0x124>(x);   // row_ror:4
    x = dpp_add<0x128>(x);   // row_ror:8
    return x;
}

// lane l gets x[l] + x[l^32] — v_permlane32_swap keeps this on the VALU pipe.
__device__ __forceinline__ float add_xor32(float x)
{
#if __has_builtin(__builtin_amdgcn_permlane32_swap)
    auto r = __builtin_amdgcn_permlane32_swap(
        __float_as_uint(x), __float_as_uint(x), false, false);
    return __uint_as_float(r[0]) + __uint_as_float(r[1]);
#else
    return x + __shfl_xor(x, 32, 64);
#endif
}

// lane l gets x[l] + x[l^16] — VALU permlane16_swap vs DS-pipe ds_swizzle.
__device__ __forceinline__ float add_xor16(float x)
{
#if __has_builtin(__builtin_amdgcn_permlane16_swap)
    auto r = __builtin_amdgcn_permlane16_swap(
        __float_as_uint(x), __float_as_uint(x), false, false);
    return __uint_as_float(r[0]) + __uint_as_float(r[1]);
#else
    return x + __int_as_float(__builtin_amdgcn_ds_swizzle(__float_as_int(x), 0x401F));
#endif
}

// ---------------------------------------------------------------------------
// 5-bit XOR swizzle on a float index within one 4096-float W tile.
// f = o*128 + d*16 + h. XOR float bits [6:2] with o (bits [11:7]) — an
// involution that keeps 16-B groups contiguous. Read-side: a wave's 64
// ds_read_b128 chunk-starts are c = (4d+2hh) ^ o, covering all 32 16-B slots
// exactly twice -> 2 lanes/bank = conflict-free floor (m136: 2-way is free).
// (The 3-bit version R1 ran leaves a 4-way conflict = 1.58x DS cost.)
// ---------------------------------------------------------------------------
__device__ __forceinline__ int wswz(int f) { return f ^ (((f >> 7) & 31) << 2); }

// Stage one 16 KB W tile global->LDS via DMA (linear LDS dest, pre-swizzled
// global source; both-sides-same-involution rule).
__device__ __forceinline__ void stage_w_tile(const float* __restrict__ wg,
                                             float* __restrict__ wn, int tid)
{
    #pragma unroll
    for (int j = 0; j < 4; j++) {
        const int P = (tid + j * 256) * 4;    // linear LDS float index
        const int g = wswz(P);                // pre-swizzled global source
        __builtin_amdgcn_global_load_lds(
            (const __attribute__((address_space(1))) void*)(wg + g),
            (__attribute__((address_space(3))) void*)(wn + P),
            16, 0, 0);
    }
}

// ---------------------------------------------------------------------------
// Pass kernel: one routing iteration. Grid (NIC, NBG) = 512 blocks x 256 thr.
// tid = o + 32*hh + 64*bq. Logits are linear in v, so vsum (= v0 [+ v1])
// replaces any logits array; PASS 0 has uniform coupling 1/32.
// Structure (R1-proven, -13 us/pass vs manual ds_write staging):
//  - W staged by global_load_lds DMA into a 2-buffer pipeline: W[i+1]'s DMA
//    issues before compute on W[i]; the end-of-iteration barrier drains it.
//  - u via broadcast global loads (wave shares bq -> same address).
//  - softmax entirely on the VALU pipe (DPP row_ror + permlane swaps).
//  - NJB=4: 8 uh-FMAs amortize one softmax + one staging quantum per thread.
// ---------------------------------------------------------------------------
template<int PASS, bool ATOMIC>
__global__ __launch_bounds__(256)
void pass_kernel(const float* __restrict__ u, const float* __restrict__ w,
                 const float* __restrict__ pv0, const float* __restrict__ pv1,
                 float* __restrict__ out)
{
    __shared__ __align__(16) float Wsh[2][WTILE];   // 2 x 16 KB, linear

    const int tid   = threadIdx.x;
    const int o     = tid & 31;
    const int hh    = (tid >> 5) & 1;
    const int bq    = tid >> 6;           // 0..3
    const int bbase = blockIdx.y * NBB;
    const int i0    = blockIdx.x * IC;
    const int hofs  = hh * 8;
    const int swm   = o << 2;             // read-side XOR (floats), 5-bit
    const int orow  = o * (DD * HH);

    // Kick off DMA for W[i0] immediately (overlaps vsum loads below).
    stage_w_tile(w + (size_t)i0 * WTILE, Wsh[0], tid);

    // vsum = sum of previous v's (constant over i).
    float vsum[NJB][8];
    if (PASS >= 1) {
        #pragma unroll
        for (int jb = 0; jb < NJB; jb++) {
            const int b = bbase + bq * NJB + jb;
            const float* p = pv0 + ((b * OO + o) * HH + hofs);
            float4 a = *(const float4*)p;
            float4 c = *(const float4*)(p + 4);
            vsum[jb][0] = a.x; vsum[jb][1] = a.y; vsum[jb][2] = a.z; vsum[jb][3] = a.w;
            vsum[jb][4] = c.x; vsum[jb][5] = c.y; vsum[jb][6] = c.z; vsum[jb][7] = c.w;
            if (PASS == 2) {
                const float* q = pv1 + ((b * OO + o) * HH + hofs);
                float4 a2 = *(const float4*)q;
                float4 c2 = *(const float4*)(q + 4);
                vsum[jb][0] += a2.x; vsum[jb][1] += a2.y; vsum[jb][2] += a2.z; vsum[jb][3] += a2.w;
                vsum[jb][4] += c2.x; vsum[jb][5] += c2.y; vsum[jb][6] += c2.z; vsum[jb][7] += c2.w;
            }
        }
    }

    float sacc[NJB][8];
    #pragma unroll
    for (int jb = 0; jb < NJB; jb++)
        #pragma unroll
        for (int h2 = 0; h2 < 8; h2++) sacc[jb][h2] = 0.f;

    __syncthreads();   // drains vmcnt(0): Wsh[0] DMA complete

    for (int ii = 0; ii < IC; ii++) {
        const float* wcur = Wsh[ii & 1];

        // Issue next tile's DMA first; it has the whole compute phase to land.
        if (ii + 1 < IC)
            stage_w_tile(w + (size_t)(i0 + ii + 1) * WTILE, Wsh[(ii + 1) & 1], tid);

        // u via broadcast global loads: whole wave shares bq -> same address.
        float us[NJB][8];
        #pragma unroll
        for (int jb = 0; jb < NJB; jb++) {
            const float* ub = u + ((size_t)(bbase + bq * NJB + jb) * II + (i0 + ii)) * DD;
            float4 a = *(const float4*)ub;
            float4 c = *(const float4*)(ub + 4);
            us[jb][0] = a.x; us[jb][1] = a.y; us[jb][2] = a.z; us[jb][3] = a.w;
            us[jb][4] = c.x; us[jb][5] = c.y; us[jb][6] = c.z; us[jb][7] = c.w;
        }

        // u_hat[b, i, o, h-half] = sum_d u[b,i,d] * W[i,o,d,h]
        float uh[NJB][8];
        #pragma unroll
        for (int jb = 0; jb < NJB; jb++)
            #pragma unroll
            for (int h2 = 0; h2 < 8; h2++) uh[jb][h2] = 0.f;
        #pragma unroll
        for (int d = 0; d < DD; d++) {
            const int ba = (d * HH + hofs    ) ^ swm;   // swizzled read offsets
            const int bb = (d * HH + hofs + 4) ^ swm;
            float4 wa = *(const float4*)&wcur[orow + ba];
            float4 wb = *(const float4*)&wcur[orow + bb];
            const float wv[8] = {wa.x, wa.y, wa.z, wa.w, wb.x, wb.y, wb.z, wb.w};
            #pragma unroll
            for (int jb = 0; jb < NJB; jb++)
                #pragma unroll
                for (int h2 = 0; h2 < 8; h2++)
                    uh[jb][h2] = fmaf(us[jb][d], wv[h2], uh[jb][h2]);
        }

        // coupling: softmax over o of (vsum . u_hat); PASS 0 -> uniform 1/32
        float cc[NJB];
        if (PASS == 0) {
            #pragma unroll
            for (int jb = 0; jb < NJB; jb++) cc[jb] = 1.0f / 32.0f;
        } else {
            #pragma unroll
            for (int jb = 0; jb < NJB; jb++) {
                float lg = 0.f;
                #pragma unroll
                for (int h2 = 0; h2 < 8; h2++)
                    lg = fmaf(vsum[jb][h2], uh[jb][h2], lg);
                lg = add_xor32(lg);                // h-half combine (VALU)
                const float e = __expf(lg);        // |lg| small -> no max-sub
                const float se = add_xor16(row_sum16(e));  // sum over 32 o-lanes (VALU)
                cc[jb] = __fdividef(e, se);
            }
        }

        #pragma unroll
        for (int jb = 0; jb < NJB; jb++)
            #pragma unroll
            for (int h2 = 0; h2 < 8; h2++)
                sacc[jb][h2] = fmaf(cc[jb], uh[jb][h2], sacc[jb][h2]);

        // barrier drains vmcnt (next tile's DMA) + lgkmcnt (our LDS reads)
        __syncthreads();
    }

    // emit partial s
    #pragma unroll
    for (int jb = 0; jb < NJB; jb++) {
        const int b = bbase + bq * NJB + jb;
        if (ATOMIC) {
            float* p = out + ((b * OO + o) * HH + hofs);
            #pragma unroll
            for (int h2 = 0; h2 < 8; h2++) atomicAdd(p + h2, sacc[jb][h2]);
        } else {
            // per-chunk slab: fully-covered contiguous lines
            float* p = out + ((size_t)blockIdx.x * BB + b) * (OO * HH) + o * HH + hofs;
            *(float4*)p       = make_float4(sacc[jb][0], sacc[jb][1], sacc[jb][2], sacc[jb][3]);
            *(float4*)(p + 4) = make_float4(sacc[jb][4], sacc[jb][5], sacc[jb][6], sacc[jb][7]);
        }
    }
}

// ---------------------------------------------------------------------------
// Fused reduce-over-chunks + squash, wide version (R4-proven): 256 blocks so
// the 16.8 MB partial read spreads over the whole chip (~4-5 us vs 18-20 us
// at 32 blocks). Block handles 32 consecutive float4 elements (t4) of
// [b][o][h]; the 128 chunks split 8-ways across thread groups (icp, 16 each),
// LDS tree combines.
// ---------------------------------------------------------------------------
__global__ __launch_bounds__(256)
void reduce_squash_wide_kernel(const float* __restrict__ part, float* __restrict__ v)
{
    const int t4l = threadIdx.x & 31;          // 0..31: which t4 in the block
    const int icp = threadIdx.x >> 5;          // 0..7: which chunk-octant
    const int t4  = blockIdx.x * 32 + t4l;     // 0..BOH/4-1

    const float4* p = (const float4*)part + t4;
    float4 acc = make_float4(0.f, 0.f, 0.f, 0.f);
    #pragma unroll
    for (int k = 0; k < NIC / 8; k++) {
        float4 x = p[(size_t)(icp * (NIC / 8) + k) * (BOH / 4)];
        acc.x += x.x; acc.y += x.y; acc.z += x.z; acc.w += x.w;
    }

    __shared__ float4 red[8][32];
    red[icp][t4l] = acc;
    __syncthreads();

    if (threadIdx.x < 32) {
        float4 a = red[0][t4l];
        #pragma unroll
        for (int j = 1; j < 8; j++) {
            float4 x = red[j][t4l];
            a.x += x.x; a.y += x.y; a.z += x.z; a.w += x.w;
        }
        // squash over h: each (b,o) is 4 consecutive t4 -> quad_perm butterfly
        float sq = a.x * a.x + a.y * a.y + a.z * a.z + a.w * a.w;
        sq = dpp_add<0xB1>(sq);   // quad_perm [1,0,3,2]
        sq = dpp_add<0x4E>(sq);   // quad_perm [2,3,0,1]
        const float scale = (sq / (1.f + sq)) * rsqrtf(sq + 1e-8f);
        a.x *= scale; a.y *= scale; a.z *= scale; a.w *= scale;
        ((float4*)v)[t4] = a;
    }
}

// Standalone squash for the atomic tiny-ws fallback.
__global__ __launch_bounds__(256)
void squash_kernel(const float* __restrict__ s, float* __restrict__ v)
{
    const int t = blockIdx.x * blockDim.x + threadIdx.x;
    if (t >= BB * OO) return;
    const float4* sp = (const float4*)(s + t * HH);
    float4 a = sp[0], b = sp[1], c = sp[2], d = sp[3];
    float sq = a.x*a.x + a.y*a.y + a.z*a.z + a.w*a.w
             + b.x*b.x + b.y*b.y + b.z*b.z + b.w*b.w
             + c.x*c.x + c.y*c.y + c.z*c.z + c.w*c.w
             + d.x*d.x + d.y*d.y + d.z*d.z + d.w*d.w;
    const float scale = (sq / (1.f + sq)) * rsqrtf(sq + 1e-8f);
    a.x *= scale; a.y *= scale; a.z *= scale; a.w *= scale;
    b.x *= scale; b.y *= scale; b.z *= scale; b.w *= scale;
    c.x *= scale; c.y *= scale; c.z *= scale; c.w *= scale;
    d.x *= scale; d.y *= scale; d.z *= scale; d.w *= scale;
    float4* vp = (float4*)(v + t * HH);
    vp[0] = a; vp[1] = b; vp[2] = c; vp[3] = d;
}

extern "C" void kernel_launch(void* const* d_in, const int* in_sizes, int n_in,
                              void* d_out, int out_size, void* d_ws, size_t ws_size,
                              hipStream_t stream)
{
    (void)in_sizes; (void)n_in; (void)out_size;
    const float* u = (const float*)d_in[0];
    const float* w = (const float*)d_in[1];
    float* out = (float*)d_out;

    const size_t need = ((size_t)NIC * BOH + 2 * BOH) * sizeof(float);  // ~17 MB
    const dim3 grid(NIC, NBG), blk(256);

    if (ws_size >= need) {
        // 6 dispatches; kernel boundaries are the (cheap) grid barrier.
        float* part = (float*)d_ws;                 // NIC x BOH partial s
        float* v0   = part + (size_t)NIC * BOH;
        float* v1   = v0 + BOH;
        const int rblocks = BOH / 4 / 32;           // 256 blocks

        pass_kernel<0, false><<<grid, blk, 0, stream>>>(u, w, nullptr, nullptr, part);
        reduce_squash_wide_kernel<<<rblocks, 256, 0, stream>>>(part, v0);
        pass_kernel<1, false><<<grid, blk, 0, stream>>>(u, w, v0, nullptr, part);
        reduce_squash_wide_kernel<<<rblocks, 256, 0, stream>>>(part, v1);
        pass_kernel<2, false><<<grid, blk, 0, stream>>>(u, w, v0, v1, part);
        reduce_squash_wide_kernel<<<rblocks, 256, 0, stream>>>(part, out);
    } else {
        // Tiny-ws fallback: atomic path.
        float* s0 = (float*)d_ws;
        float* s1 = s0 + BOH;
        float* v0 = s1 + BOH;
        float* v1 = v0 + BOH;
        hipMemsetAsync(d_ws, 0, 2 * BOH * sizeof(float), stream);
        hipMemsetAsync(d_out, 0, BOH * sizeof(float), stream);
        const int sq_blocks = (BB * OO + 255) / 256;

        pass_kernel<0, true><<<grid, blk, 0, stream>>>(u, w, nullptr, nullptr, s0);
        squash_kernel<<<sq_blocks, 256, 0, stream>>>(s0, v0);
        pass_kernel<1, true><<<grid, blk, 0, stream>>>(u, w, v0, nullptr, s1);
        squash_kernel<<<sq_blocks, 256, 0, stream>>>(s1, v1);
        pass_kernel<2, true><<<grid, blk, 0, stream>>>(u, w, v0, v1, out);
        squash_kernel<<<sq_blocks, 256, 0, stream>>>(out, out);
    }
}